// Round 1
// baseline (16502.496 us; speedup 1.0000x reference)
//
#include <hip/hip_runtime.h>
#include <hip/hip_cooperative_groups.h>

namespace cg = cooperative_groups;

typedef _Float16 f16;
typedef f16 f16x8 __attribute__((ext_vector_type(8)));
typedef float f32x4 __attribute__((ext_vector_type(4)));

#define TSTEPS 128
#define NBLK 256
#define NTHR 256

// ---------------- workspace layout (bytes) ----------------
#define WT_BYTES   (3ull*128*32*64*16)            // swizzled f16 weights: 12,582,912
#define H_OFF      (WT_BYTES)
#define H_BYTES    (3ull*2*768*512*2)             // h double buffers (f16): 4,718,592
#define C_OFF      (H_OFF + H_BYTES)
#define C_BYTES    (3ull*768*512*4)               // c state (f32): 4,718,592
#define M1_OFF     (C_OFF + C_BYTES)
#define R1_OFF     (M1_OFF + 1536*4)
#define Y1_OFF     (R1_OFF + 1536*4)
#define M2_OFF     (Y1_OFF + 256ull*1024*4)
#define R2_OFF     (M2_OFF + 1024*4)
#define Y2_OFF     (R2_OFF + 1024*4)
#define M3_OFF     (Y2_OFF + 256ull*102*4)
#define R3_OFF     (M3_OFF + 128*4)
#define WS_NEED    (R3_OFF + 128*4)               // ~23.2 MB

struct Params {
  const int *t1, *t2, *t3;
  const float *emb, *lW, *lB;
  const float *g1, *be1, *W1, *b1;
  const float *g2, *be2, *W2, *b2;
  const float *g3, *be3, *W3, *b3;
  float* out;
  unsigned char* ws;
};

__device__ __forceinline__ float sigmf(float x) {
  x = fminf(fmaxf(x, -30.f), 30.f);
  return 1.f / (1.f + __expf(-x));
}
__device__ __forceinline__ float tanhf_(float x) {
  x = fminf(fmaxf(x, -15.f), 15.f);
  float e = __expf(-2.f * x);
  return (1.f - e) / (1.f + e);
}

// block stats over 256 batch rows -> mean, rsqrt(var+eps)
__device__ __forceinline__ void colstats(float v, int tid, float* red,
                                         float* mout, float* rout, int c) {
  red[tid] = v; red[256 + tid] = v * v;
  __syncthreads();
  for (int off = 128; off > 0; off >>= 1) {
    if (tid < off) { red[tid] += red[tid + off]; red[256 + tid] += red[256 + tid + off]; }
    __syncthreads();
  }
  if (tid == 0) {
    float mu = red[0] * (1.f / 256.f);
    float var = red[256] * (1.f / 256.f) - mu * mu;
    mout[c] = mu; rout[c] = rsqrtf(var + 1e-3f);
  }
  __syncthreads();
}

__global__ __launch_bounds__(NTHR) void conv_lstm(Params P) {
  cg::grid_group grid = cg::this_grid();
  const int bid = blockIdx.x, tid = threadIdx.x;

  f16*   WT = (f16*)(P.ws);
  f16*   Hb = (f16*)(P.ws + H_OFF);
  float* Cb = (float*)(P.ws + C_OFF);

  // A-staging LDS: 48 frag-blocks (6 row-tiles x 8 k-tiles) of 64 lanes*16B, +16B pad each
  __shared__ __align__(16) unsigned char smem[50176];
  __shared__ float red[512];

  // ---- phase -1: weight f32->f16 swizzle into MFMA B-fragment order + zero h/c ----
  {
    const int gt = bid * NTHR + tid;
    // out-index iteration: slot = ((l*128+g16)*32+kkg)*64+lane ; each slot = 8 f16
    for (int slot = gt; slot < 786432; slot += NBLK * NTHR) {
      int lane = slot & 63, kkg = (slot >> 6) & 31, g16 = (slot >> 11) & 127, l = slot >> 18;
      int k = kkg * 32 + (lane >> 4) * 8;         // k of j=0
      int p = g16 * 16 + (lane & 15);             // permuted gate-col: p = 4u+g
      int n = (p & 3) * 512 + (p >> 2);           // original col: g*512+u
      const float* s = P.lW + ((size_t)l * 1024 + k) * 2048 + n;
      f16x8 v;
      #pragma unroll
      for (int j = 0; j < 8; j++) v[j] = (f16)s[(size_t)j * 2048];
      *(f16x8*)(WT + (size_t)slot * 8) = v;
    }
    uint4 z4; z4.x = z4.y = z4.z = z4.w = 0u;
    uint4* zp = (uint4*)(P.ws + H_OFF);           // h then c, contiguous
    for (int i = gt; i < 589824; i += NBLK * NTHR) zp[i] = z4;
  }
  grid.sync();

  const int rg = bid >> 5, cgi = bid & 31;        // 8 row-groups x 32 col-groups
  const int w = tid >> 6, L = tid & 63;
  const int wrg = w >> 1, wct = w & 1;            // wave: row-half, col-half
  const int row0 = rg * 96;
  const int r16 = L & 15, quad = L >> 4, gg = L & 3;

  // ---- wavefront over (layer, time): step s handles layer l at t=s-l ----
  for (int s = 0; s < TSTEPS + 2; ++s) {
    for (int l = 0; l < 3; ++l) {
      const int t = s - l;
      if (t < 0 || t >= TSTEPS) continue;
      const f16* hx  = Hb + (size_t)((l ? l - 1 : 0) * 2 + (t & 1)) * 768 * 512;  // x-src (l>0)
      const f16* hh  = Hb + (size_t)(l * 2 + ((t - 1) & 1)) * 768 * 512;          // h_prev
      f16*       hdo = Hb + (size_t)(l * 2 + (t & 1)) * 768 * 512;                // h out

      f32x4 acc[3][2];
      #pragma unroll
      for (int a = 0; a < 3; a++)
        #pragma unroll
        for (int b = 0; b < 2; b++) acc[a][b] = (f32x4){0.f, 0.f, 0.f, 0.f};

      for (int chunk = 0; chunk < 4; ++chunk) {   // K=1024 in 4x256
        __syncthreads();
        for (int i = 0; i < 12; ++i) {            // stage A-chunk [96 x 256] f16
          int idx = tid + i * NTHR;               // 0..3071
          int arow = idx >> 5, kseg = idx & 31;
          int kg = chunk * 256 + kseg * 8;
          int m = row0 + arow;
          unsigned char* dst = smem + (size_t)((arow >> 4) * 8 + (kseg >> 2)) * 1040
                                    + ((kseg & 3) * 16 + (arow & 15)) * 16;
          if (kg < 512) {                         // x-part
            if (l == 0) {
              int b = m & 255, tx = m >> 8;
              const int* tp = (tx == 0) ? P.t1 : ((tx == 1) ? P.t2 : P.t3);
              int tok = tp[b * TSTEPS + t];
              const float* e = P.emb + (size_t)tok * 512 + kg;
              float4 fa = *(const float4*)e, fb = *(const float4*)(e + 4);
              f16x8 v;
              v[0]=(f16)fa.x; v[1]=(f16)fa.y; v[2]=(f16)fa.z; v[3]=(f16)fa.w;
              v[4]=(f16)fb.x; v[5]=(f16)fb.y; v[6]=(f16)fb.z; v[7]=(f16)fb.w;
              *(f16x8*)dst = v;
            } else {
              *(uint4*)dst = *(const uint4*)(hx + (size_t)m * 512 + kg);
            }
          } else {                                // h-part
            *(uint4*)dst = *(const uint4*)(hh + (size_t)m * 512 + (kg - 512));
          }
        }
        __syncthreads();
        // B fragments straight from global (pre-swizzled, 16B/lane contiguous)
        const f16x8* Bb = (const f16x8*)WT
            + ((size_t)(l * 128 + cgi * 4 + wct * 2) * 32 + chunk * 8) * 64 + L;
        #pragma unroll
        for (int kk = 0; kk < 8; ++kk) {
          f16x8 a0 = *(const f16x8*)(smem + ((wrg * 3 + 0) * 8 + kk) * 1040 + L * 16);
          f16x8 a1 = *(const f16x8*)(smem + ((wrg * 3 + 1) * 8 + kk) * 1040 + L * 16);
          f16x8 a2 = *(const f16x8*)(smem + ((wrg * 3 + 2) * 8 + kk) * 1040 + L * 16);
          f16x8 b0 = Bb[kk * 64];
          f16x8 b1 = Bb[2048 + kk * 64];
          acc[0][0] = __builtin_amdgcn_mfma_f32_16x16x32_f16(a0, b0, acc[0][0], 0, 0, 0);
          acc[1][0] = __builtin_amdgcn_mfma_f32_16x16x32_f16(a1, b0, acc[1][0], 0, 0, 0);
          acc[2][0] = __builtin_amdgcn_mfma_f32_16x16x32_f16(a2, b0, acc[2][0], 0, 0, 0);
          acc[0][1] = __builtin_amdgcn_mfma_f32_16x16x32_f16(a0, b1, acc[0][1], 0, 0, 0);
          acc[1][1] = __builtin_amdgcn_mfma_f32_16x16x32_f16(a1, b1, acc[1][1], 0, 0, 0);
          acc[2][1] = __builtin_amdgcn_mfma_f32_16x16x32_f16(a2, b1, acc[2][1], 0, 0, 0);
        }
      }

      // elementwise: gates i,j,f,o live in 4 adjacent lanes (p = 4u+g) -> shfl_xor
      #pragma unroll
      for (int ct2 = 0; ct2 < 2; ++ct2) {
        int u = cgi * 16 + wct * 8 + ct2 * 4 + (r16 >> 2);
        float bias = P.lB[l * 2048 + gg * 512 + u];
        #pragma unroll
        for (int rt = 0; rt < 3; ++rt) {
          #pragma unroll
          for (int r = 0; r < 4; ++r) {
            float v = acc[rt][ct2][r] + bias;
            float vj = __shfl_xor(v, 1, 64);
            float vf = __shfl_xor(v, 2, 64);
            float vo = __shfl_xor(v, 3, 64);
            if (gg == 0) {
              int m = row0 + wrg * 48 + rt * 16 + quad * 4 + r;
              size_t ci = ((size_t)l * 768 + m) * 512 + u;
              float cold = Cb[ci];
              float cn = sigmf(vf) * cold + sigmf(v) * tanhf_(vj);
              Cb[ci] = cn;
              hdo[(size_t)m * 512 + u] = (f16)(sigmf(vo) * tanhf_(cn));
            }
          }
        }
      }
    }
    grid.sync();
  }

  // ---------------- epilogue: BN1 -> FC1+SELU -> BN2 -> FC2+SELU -> BN3 -> FC3 ----------------
  float* mean1 = (float*)(P.ws + M1_OFF); float* rstd1 = (float*)(P.ws + R1_OFF);
  float* y1    = (float*)(P.ws + Y1_OFF);
  float* mean2 = (float*)(P.ws + M2_OFF); float* rstd2 = (float*)(P.ws + R2_OFF);
  float* y2    = (float*)(P.ws + Y2_OFF);
  float* mean3 = (float*)(P.ws + M3_OFF); float* rstd3 = (float*)(P.ws + R3_OFF);
  const f16* h2f = Hb + (size_t)(2 * 2 + 1) * 768 * 512;   // top layer, t=127 (buf 1)

  // E1: BN1 stats over batch for 1536 cols (6 per block)
  for (int i = 0; i < 6; ++i) {
    int c = bid * 6 + i;
    int txo = (c >> 9) * 256, u = c & 511;
    float v = (float)h2f[(size_t)(txo + tid) * 512 + u];
    colstats(v, tid, red, mean1, rstd1, c);
  }
  grid.sync();

  // E2: y1 = selu(rep_n @ W1 + b1)   [256 x 1024]
  {
    float* ash = (float*)smem;                  // [16][768]
    int bb = (bid >> 4) * 16, nb = (bid & 15) * 64;
    int rgrp = tid >> 6, nlane = tid & 63;
    float accv[4] = {0.f, 0.f, 0.f, 0.f};
    for (int kc = 0; kc < 2; ++kc) {
      __syncthreads();
      for (int idx = tid; idx < 16 * 768; idx += NTHR) {
        int rr = idx / 768, cc = idx - rr * 768;
        int c = kc * 768 + cc;
        int txo = (c >> 9) * 256, u = c & 511;
        float v = (float)h2f[(size_t)(txo + bb + rr) * 512 + u];
        ash[rr * 768 + cc] = (v - mean1[c]) * rstd1[c] * P.g1[c] + P.be1[c];
      }
      __syncthreads();
      for (int k = 0; k < 768; ++k) {
        float wv = P.W1[(size_t)(kc * 768 + k) * 1024 + nb + nlane];
        #pragma unroll
        for (int rr = 0; rr < 4; ++rr) accv[rr] += ash[(rgrp * 4 + rr) * 768 + k] * wv;
      }
    }
    const float sc = 1.0507009873554805f, al = 1.6732632423543772f;
    #pragma unroll
    for (int rr = 0; rr < 4; ++rr) {
      int b = bb + rgrp * 4 + rr, n = nb + nlane;
      float x = accv[rr] + P.b1[n];
      y1[(size_t)b * 1024 + n] = sc * (x > 0.f ? x : al * expm1f(x));
    }
  }
  grid.sync();

  // E3: BN2 stats (4 cols per block)
  for (int i = 0; i < 4; ++i) {
    int c = bid * 4 + i;
    float v = y1[(size_t)tid * 1024 + c];
    colstats(v, tid, red, mean2, rstd2, c);
  }
  grid.sync();

  // E4: y2 = selu(y1n @ W2 + b2)   [256 x 102]; one row per block
  {
    float* ysh = (float*)smem;                  // [1024]
    int b = bid;
    __syncthreads();
    for (int k = tid; k < 1024; k += NTHR)
      ysh[k] = (y1[(size_t)b * 1024 + k] - mean2[k]) * rstd2[k] * P.g2[k] + P.be2[k];
    __syncthreads();
    const float sc = 1.0507009873554805f, al = 1.6732632423543772f;
    for (int c = tid; c < 102; c += NTHR) {
      float a = 0.f;
      for (int k = 0; k < 1024; ++k) a += ysh[k] * P.W2[(size_t)k * 102 + c];
      float x = a + P.b2[c];
      y2[(size_t)b * 102 + c] = sc * (x > 0.f ? x : al * expm1f(x));
    }
  }
  grid.sync();

  // E5: BN3 stats (1 col per block, first 102 blocks)
  if (bid < 102) {
    int c = bid;
    float v = y2[(size_t)tid * 102 + c];
    colstats(v, tid, red, mean3, rstd3, c);
  }
  grid.sync();

  // E6: out = y2n @ W3 + b3   [256 x 4]; one row per block
  {
    int b = bid;
    if (tid < 4) {
      float a = P.b3[tid];
      for (int k = 0; k < 102; ++k) {
        float yv = (y2[(size_t)b * 102 + k] - mean3[k]) * rstd3[k] * P.g3[k] + P.be3[k];
        a += yv * P.W3[k * 4 + tid];
      }
      P.out[b * 4 + tid] = a;
    }
  }
}

extern "C" void kernel_launch(void* const* d_in, const int* in_sizes, int n_in,
                              void* d_out, int out_size, void* d_ws, size_t ws_size,
                              hipStream_t stream) {
  if (ws_size < (size_t)WS_NEED) return;  // workspace too small -> fail validation cleanly
  Params prm;
  prm.t1  = (const int*)d_in[0];
  prm.t2  = (const int*)d_in[1];
  prm.t3  = (const int*)d_in[2];
  prm.emb = (const float*)d_in[3];
  prm.lW  = (const float*)d_in[4];
  prm.lB  = (const float*)d_in[5];
  prm.g1  = (const float*)d_in[6];  prm.be1 = (const float*)d_in[7];
  prm.W1  = (const float*)d_in[8];  prm.b1  = (const float*)d_in[9];
  prm.g2  = (const float*)d_in[10]; prm.be2 = (const float*)d_in[11];
  prm.W2  = (const float*)d_in[12]; prm.b2  = (const float*)d_in[13];
  prm.g3  = (const float*)d_in[14]; prm.be3 = (const float*)d_in[15];
  prm.W3  = (const float*)d_in[16]; prm.b3  = (const float*)d_in[17];
  prm.out = (float*)d_out;
  prm.ws  = (unsigned char*)d_ws;
  void* args[] = { &prm };
  hipLaunchCooperativeKernel((void*)conv_lstm, dim3(NBLK), dim3(NTHR), args, 0, stream);
}

// Round 3
// 11095.692 us; speedup vs baseline: 1.4873x; 1.4873x over previous
//
#include <hip/hip_runtime.h>
#include <hip/hip_cooperative_groups.h>

namespace cg = cooperative_groups;

typedef _Float16 f16;
typedef f16 f16x8 __attribute__((ext_vector_type(8)));
typedef float f32x4 __attribute__((ext_vector_type(4)));

#define TSTEPS 128
#define NBLK 256
#define NTHR 768

// ---------------- workspace layout (bytes) ----------------
#define WT_BYTES (3ull*128*32*64*16)            // swizzled f16 weights: 12,582,912
#define H_OFF    (WT_BYTES)
#define H_BYTES  (3ull*2*768*512*2)             // h double buffers (f16): 4,718,592
#define S1_OFF   (H_OFF + H_BYTES)              // scale1[1536]
#define O1_OFF   (S1_OFF + 1536*4)              // offset1[1536]
#define Y1_OFF   (O1_OFF + 1536*4)
#define S2_OFF   (Y1_OFF + 256ull*1024*4)
#define O2_OFF   (S2_OFF + 1024*4)
#define Y2_OFF   (O2_OFF + 1024*4)
#define S3_OFF   (Y2_OFF + 256ull*102*4)
#define O3_OFF   (S3_OFF + 128*4)
#define WS_NEED  (O3_OFF + 128*4)               // ~18.5 MB

struct Params {
  const int *t1, *t2, *t3;
  const float *emb, *lW, *lB;
  const float *g1, *be1, *W1, *b1;
  const float *g2, *be2, *W2, *b2;
  const float *g3, *be3, *W3, *b3;
  float* out;
  unsigned char* ws;
};

__device__ __forceinline__ float sigmf(float x) {
  x = fminf(fmaxf(x, -30.f), 30.f);
  return 1.f / (1.f + __expf(-x));
}
__device__ __forceinline__ float tanhf_(float x) {
  x = fminf(fmaxf(x, -15.f), 15.f);
  float e = __expf(-2.f * x);
  return (1.f - e) / (1.f + e);
}
__device__ __forceinline__ float wsum(float v) {
  #pragma unroll
  for (int m = 1; m < 64; m <<= 1) v += __shfl_xor(v, m, 64);
  return v;
}
__device__ __forceinline__ f16x8 emb_frag(const float* e) {
  float4 fa = *(const float4*)e, fb = *(const float4*)(e + 4);
  f16x8 v;
  v[0]=(f16)fa.x; v[1]=(f16)fa.y; v[2]=(f16)fa.z; v[3]=(f16)fa.w;
  v[4]=(f16)fb.x; v[5]=(f16)fb.y; v[6]=(f16)fb.z; v[7]=(f16)fb.w;
  return v;
}
#define MFMA16(a,b,c) __builtin_amdgcn_mfma_f32_16x16x32_f16((a),(b),(c),0,0,0)

// 256 blocks x 768 threads: exactly 1 block/CU (proven cooperative shape).
// launch_bounds(768,3): 12 waves/block need 3 waves/EU -> VGPR capped <=168.
__global__ __launch_bounds__(NTHR, 3) void conv_lstm(Params P) {
  cg::grid_group grid = cg::this_grid();
  const int bid = blockIdx.x, tid = threadIdx.x;

  f16* WT = (f16*)(P.ws);
  f16* Hb = (f16*)(P.ws + H_OFF);

  // ---- phase -1: weight f32->f16 swizzle into MFMA B-fragment order + zero h ----
  {
    const int gt = bid * NTHR + tid;
    for (int slot = gt; slot < 786432; slot += NBLK * NTHR) {
      int lane = slot & 63, kkg = (slot >> 6) & 31, g16 = (slot >> 11) & 127, l = slot >> 18;
      int k = kkg * 32 + (lane >> 4) * 8;         // k of j=0
      int p = g16 * 16 + (lane & 15);             // permuted gate-col: p = 4u+g
      int n = (p & 3) * 512 + (p >> 2);           // original col: g*512+u
      const float* s = P.lW + ((size_t)l * 1024 + k) * 2048 + n;
      f16x8 v;
      #pragma unroll
      for (int j = 0; j < 8; j++) v[j] = (f16)s[(size_t)j * 2048];
      *(f16x8*)(WT + (size_t)slot * 8) = v;
    }
    uint4 z4; z4.x = z4.y = z4.z = z4.w = 0u;
    uint4* zp = (uint4*)(P.ws + H_OFF);
    for (int i = gt; i < 294912; i += NBLK * NTHR) zp[i] = z4;
  }
  grid.sync();

  // ---- thread geometry ----
  const int sb   = tid >> 8;                      // layer (sub-group of 256 threads)
  const int tid2 = tid & 255;
  const int w2   = tid2 >> 6, L = tid2 & 63;
  const int wrg  = w2 >> 1, wct = w2 & 1;
  const int r16  = L & 15, quad = L >> 4;
  const int s4   = L & 3, r16q = r16 >> 2;
  const int rg   = bid >> 5, cgi = bid & 31;      // bid%8 = cgi%8 -> weights L2-local/XCD
  const int row0 = rg * 96;

  // elementwise: lane owns (row quad*4+s4 per rt) x (unit ug + ct2*4); gates in regs
  const int ug = cgi * 16 + wct * 8 + r16q;
  float bia[2][4];
  #pragma unroll
  for (int ct2 = 0; ct2 < 2; ++ct2)
    #pragma unroll
    for (int g = 0; g < 4; ++g)
      bia[ct2][g] = P.lB[sb * 2048 + g * 512 + ug + ct2 * 4];
  float c6[6] = {0.f, 0.f, 0.f, 0.f, 0.f, 0.f};

  const int mrow0 = row0 + wrg * 48 + 0 * 16 + r16;
  const int mrow1 = row0 + wrg * 48 + 1 * 16 + r16;
  const int mrow2 = row0 + wrg * 48 + 2 * 16 + r16;
  const size_t lstride = 768 * 512;

  const f16x8* Bb = (const f16x8*)WT
      + ((size_t)(sb * 128 + cgi * 4 + wct * 2) * 32) * 64 + L;

  // ---- wavefront: 3 layers in parallel (disjoint sub-groups), no intra-step barriers ----
  for (int s = 0; s < TSTEPS + 2; ++s) {
    const int t = s - sb;
    if (t >= 0 && t < TSTEPS) {
      const f16* hx  = Hb + (size_t)((sb ? sb - 1 : 0) * 2 + (t & 1)) * lstride;
      const f16* hh  = Hb + (size_t)(sb * 2 + ((t - 1) & 1)) * lstride;
      f16*       hdo = Hb + (size_t)(sb * 2 + (t & 1)) * lstride;

      f32x4 acc[3][2];
      #pragma unroll
      for (int a = 0; a < 3; a++)
        #pragma unroll
        for (int b = 0; b < 2; b++) acc[a][b] = (f32x4){0.f, 0.f, 0.f, 0.f};

      // token/emb base pointers for layer 0 (per-lane row -> tx, b)
      const float *e0, *e1, *e2;
      if (sb == 0) {
        int b0 = mrow0 & 255, tx0 = mrow0 >> 8;
        int b1 = mrow1 & 255, tx1 = mrow1 >> 8;
        int b2 = mrow2 & 255, tx2 = mrow2 >> 8;
        const int* tp0 = (tx0 == 0) ? P.t1 : ((tx0 == 1) ? P.t2 : P.t3);
        const int* tp1 = (tx1 == 0) ? P.t1 : ((tx1 == 1) ? P.t2 : P.t3);
        const int* tp2 = (tx2 == 0) ? P.t1 : ((tx2 == 1) ? P.t2 : P.t3);
        e0 = P.emb + (size_t)tp0[b0 * TSTEPS + t] * 512;
        e1 = P.emb + (size_t)tp1[b1 * TSTEPS + t] * 512;
        e2 = P.emb + (size_t)tp2[b2 * TSTEPS + t] * 512;
      }

      // x-side: k in [0,512)
      #pragma unroll 4
      for (int kk = 0; kk < 16; ++kk) {
        int k = kk * 32 + quad * 8;
        f16x8 a0, a1, a2;
        if (sb == 0) {
          a0 = emb_frag(e0 + k); a1 = emb_frag(e1 + k); a2 = emb_frag(e2 + k);
        } else {
          a0 = *(const f16x8*)(hx + (size_t)mrow0 * 512 + k);
          a1 = *(const f16x8*)(hx + (size_t)mrow1 * 512 + k);
          a2 = *(const f16x8*)(hx + (size_t)mrow2 * 512 + k);
        }
        f16x8 b0 = Bb[kk * 64], b1 = Bb[kk * 64 + 2048];
        acc[0][0] = MFMA16(a0, b0, acc[0][0]);
        acc[1][0] = MFMA16(a1, b0, acc[1][0]);
        acc[2][0] = MFMA16(a2, b0, acc[2][0]);
        acc[0][1] = MFMA16(a0, b1, acc[0][1]);
        acc[1][1] = MFMA16(a1, b1, acc[1][1]);
        acc[2][1] = MFMA16(a2, b1, acc[2][1]);
      }
      // h-side: k in [512,1024)
      #pragma unroll 4
      for (int kk = 16; kk < 32; ++kk) {
        int k2 = kk * 32 - 512 + quad * 8;
        f16x8 a0 = *(const f16x8*)(hh + (size_t)mrow0 * 512 + k2);
        f16x8 a1 = *(const f16x8*)(hh + (size_t)mrow1 * 512 + k2);
        f16x8 a2 = *(const f16x8*)(hh + (size_t)mrow2 * 512 + k2);
        f16x8 b0 = Bb[kk * 64], b1 = Bb[kk * 64 + 2048];
        acc[0][0] = MFMA16(a0, b0, acc[0][0]);
        acc[1][0] = MFMA16(a1, b0, acc[1][0]);
        acc[2][0] = MFMA16(a2, b0, acc[2][0]);
        acc[0][1] = MFMA16(a0, b1, acc[0][1]);
        acc[1][1] = MFMA16(a1, b1, acc[1][1]);
        acc[2][1] = MFMA16(a2, b1, acc[2][1]);
      }

      // ---- elementwise: 4x4 lane<->reg transpose puts all 4 gates in one lane ----
      #pragma unroll
      for (int rt = 0; rt < 3; ++rt) {
        #pragma unroll
        for (int ct2 = 0; ct2 < 2; ++ct2) {
          float x0 = acc[rt][ct2][0], x1 = acc[rt][ct2][1];
          float x2 = acc[rt][ct2][2], x3 = acc[rt][ct2][3];
          float a, b;
          a = (s4 & 1) ? x0 : x1;  b = (s4 & 1) ? x2 : x3;
          a = __shfl_xor(a, 1, 64); b = __shfl_xor(b, 1, 64);
          if (s4 & 1) { x0 = a; x2 = b; } else { x1 = a; x3 = b; }
          a = (s4 & 2) ? x0 : x2;  b = (s4 & 2) ? x1 : x3;
          a = __shfl_xor(a, 2, 64); b = __shfl_xor(b, 2, 64);
          if (s4 & 2) { x0 = a; x1 = b; } else { x2 = a; x3 = b; }
          // lane now holds {i,j,f,o} for row quad*4+s4, unit ug+ct2*4
          float vi = x0 + bia[ct2][0], vj = x1 + bia[ct2][1];
          float vf = x2 + bia[ct2][2], vo = x3 + bia[ct2][3];
          int j = rt * 2 + ct2;
          float cn = sigmf(vf) * c6[j] + sigmf(vi) * tanhf_(vj);
          c6[j] = cn;
          int m = row0 + wrg * 48 + rt * 16 + quad * 4 + s4;
          hdo[(size_t)m * 512 + ug + ct2 * 4] = (f16)(sigmf(vo) * tanhf_(cn));
        }
      }
    }
    grid.sync();
  }

  // ---------------- epilogue (wave-granular, shfl-only, no barriers) ----------------
  float* scale1 = (float*)(P.ws + S1_OFF); float* off1 = (float*)(P.ws + O1_OFF);
  float* y1     = (float*)(P.ws + Y1_OFF);
  float* scale2 = (float*)(P.ws + S2_OFF); float* off2 = (float*)(P.ws + O2_OFF);
  float* y2     = (float*)(P.ws + Y2_OFF);
  float* scale3 = (float*)(P.ws + S3_OFF); float* off3 = (float*)(P.ws + O3_OFF);
  const f16* h2f = Hb + (size_t)(2 * 2 + 1) * lstride;   // top layer, t=127 (slot 1)

  const int wvg = bid * 12 + (tid >> 6);
  const int Le  = tid & 63;
  const float SC = 1.0507009873554805f, AL = 1.6732632423543772f;

  // E1: BN1 -> fused scale/offset for 1536 cols (one wave per col)
  if (wvg < 1536) {
    int c = wvg, tx = c >> 9, u = c & 511;
    float sm = 0.f, s2 = 0.f;
    for (int r = Le; r < 256; r += 64) {
      float v = (float)h2f[(size_t)(tx * 256 + r) * 512 + u];
      sm += v; s2 += v * v;
    }
    sm = wsum(sm); s2 = wsum(s2);
    if (Le == 0) {
      float mu = sm * (1.f / 256.f);
      float var = s2 * (1.f / 256.f) - mu * mu;
      float sc = rsqrtf(var + 1e-3f) * P.g1[c];
      scale1[c] = sc; off1[c] = P.be1[c] - mu * sc;
    }
  }
  grid.sync();

  // E2: y1 = selu(rep_n @ W1 + b1): 1024 waves, tile 16 rows x 16 cols
  if (wvg < 1024) {
    int rb = wvg >> 6, cb = wvg & 63;
    int cL = Le & 15, rq = Le >> 4;
    int col = cb * 16 + cL;
    float accv[4] = {0.f, 0.f, 0.f, 0.f};
    for (int k = 0; k < 1536; ++k) {
      int tx = k >> 9, u = k & 511;
      float sc = scale1[k], of = off1[k];
      float wv = P.W1[(size_t)k * 1024 + col];
      #pragma unroll
      for (int rr = 0; rr < 4; ++rr) {
        int row = rb * 16 + rq * 4 + rr;
        float v = (float)h2f[(size_t)(tx * 256 + row) * 512 + u] * sc + of;
        accv[rr] += v * wv;
      }
    }
    #pragma unroll
    for (int rr = 0; rr < 4; ++rr) {
      int row = rb * 16 + rq * 4 + rr;
      float x = accv[rr] + P.b1[col];
      y1[(size_t)row * 1024 + col] = SC * (x > 0.f ? x : AL * expm1f(x));
    }
  }
  grid.sync();

  // E3: BN2 scale/offset for 1024 cols (one wave per col)
  if (wvg < 1024) {
    int c = wvg;
    float sm = 0.f, s2 = 0.f;
    for (int r = Le; r < 256; r += 64) {
      float v = y1[(size_t)r * 1024 + c];
      sm += v; s2 += v * v;
    }
    sm = wsum(sm); s2 = wsum(s2);
    if (Le == 0) {
      float mu = sm * (1.f / 256.f);
      float var = s2 * (1.f / 256.f) - mu * mu;
      float sc = rsqrtf(var + 1e-3f) * P.g2[c];
      scale2[c] = sc; off2[c] = P.be2[c] - mu * sc;
    }
  }
  grid.sync();

  // E4: y2 = selu(y1n @ W2 + b2): one wave per batch row; lane covers cols Le, Le+64
  if (wvg < 256) {
    int row = wvg;
    int c0 = Le, c1 = Le + 64;
    float a0 = 0.f, a1 = 0.f;
    for (int k = 0; k < 1024; ++k) {
      float v = y1[(size_t)row * 1024 + k] * scale2[k] + off2[k];
      a0 += v * P.W2[(size_t)k * 102 + c0];
      if (c1 < 102) a1 += v * P.W2[(size_t)k * 102 + c1];
    }
    {
      float x = a0 + P.b2[c0];
      if (c0 < 102) y2[(size_t)row * 102 + c0] = SC * (x > 0.f ? x : AL * expm1f(x));
    }
    if (c1 < 102) {
      float x = a1 + P.b2[c1];
      y2[(size_t)row * 102 + c1] = SC * (x > 0.f ? x : AL * expm1f(x));
    }
  }
  grid.sync();

  // E5: BN3 scale/offset for 102 cols (one wave per col)
  if (wvg < 102) {
    int c = wvg;
    float sm = 0.f, s2 = 0.f;
    for (int r = Le; r < 256; r += 64) {
      float v = y2[(size_t)r * 102 + c];
      sm += v; s2 += v * v;
    }
    sm = wsum(sm); s2 = wsum(s2);
    if (Le == 0) {
      float mu = sm * (1.f / 256.f);
      float var = s2 * (1.f / 256.f) - mu * mu;
      float sc = rsqrtf(var + 1e-3f) * P.g3[c];
      scale3[c] = sc; off3[c] = P.be3[c] - mu * sc;
    }
  }
  grid.sync();

  // E6: out = y2n @ W3 + b3: one wave per batch row; lane = (kk = Le>>2, c = Le&3)
  if (wvg < 256) {
    int row = wvg;
    int c = Le & 3, kq = Le >> 2;
    float part = 0.f;
    for (int k = kq; k < 102; k += 16) {
      float v = y2[(size_t)row * 102 + k] * scale3[k] + off3[k];
      part += v * P.W3[k * 4 + c];
    }
    #pragma unroll
    for (int m = 4; m < 64; m <<= 1) part += __shfl_xor(part, m, 64);
    if (Le < 4) P.out[row * 4 + Le] = part + P.b3[Le];
  }
}

extern "C" void kernel_launch(void* const* d_in, const int* in_sizes, int n_in,
                              void* d_out, int out_size, void* d_ws, size_t ws_size,
                              hipStream_t stream) {
  if (ws_size < (size_t)WS_NEED) return;
  Params prm;
  prm.t1  = (const int*)d_in[0];
  prm.t2  = (const int*)d_in[1];
  prm.t3  = (const int*)d_in[2];
  prm.emb = (const float*)d_in[3];
  prm.lW  = (const float*)d_in[4];
  prm.lB  = (const float*)d_in[5];
  prm.g1  = (const float*)d_in[6];  prm.be1 = (const float*)d_in[7];
  prm.W1  = (const float*)d_in[8];  prm.b1  = (const float*)d_in[9];
  prm.g2  = (const float*)d_in[10]; prm.be2 = (const float*)d_in[11];
  prm.W2  = (const float*)d_in[12]; prm.b2  = (const float*)d_in[13];
  prm.g3  = (const float*)d_in[14]; prm.be3 = (const float*)d_in[15];
  prm.W3  = (const float*)d_in[16]; prm.b3  = (const float*)d_in[17];
  prm.out = (float*)d_out;
  prm.ws  = (unsigned char*)d_ws;
  void* args[] = { &prm };
  hipLaunchCooperativeKernel((void*)conv_lstm, dim3(NBLK), dim3(NTHR), args, 0, stream);
}